// Round 1
// 183.894 us; speedup vs baseline: 1.0347x; 1.0347x over previous
//
#include <hip/hip_runtime.h>
#include <math.h>

// Problem constants (MultiHeadAttention_19344532701482)
static constexpr int Bc  = 2;
static constexpr int Sc  = 2048;
static constexpr int Dc  = 1024;
static constexpr int Hc  = 16;
static constexpr int DHc = 64;

typedef short bf16x8 __attribute__((ext_vector_type(8)));  // MFMA A/B frag
typedef float f32x4  __attribute__((ext_vector_type(4)));  // MFMA C/D frag

static constexpr float LOG2E = 1.4426950408889634f;

// fp32 -> bf16 round-to-nearest-even
static __device__ __forceinline__ unsigned short f2bf(float x) {
  union { float f; unsigned u; } v; v.f = x;
  unsigned r = v.u + 0x7FFFu + ((v.u >> 16) & 1u);
  return (unsigned short)(r >> 16);
}
static __device__ __forceinline__ float bf2f(unsigned short u) {
  union { unsigned u; float f; } v; v.u = ((unsigned)u) << 16;
  return v.f;
}
// pack trunc-bf16(a) [low] , trunc-bf16(b) [high] in one v_perm_b32
static __device__ __forceinline__ unsigned pk2bf_trunc(float a, float b) {
  return __builtin_amdgcn_perm(__float_as_uint(b), __float_as_uint(a), 0x07060302u);
}
#if __has_builtin(__builtin_amdgcn_exp2f)
#define EXP2F(x) __builtin_amdgcn_exp2f(x)
#else
#define EXP2F(x) exp2f(x)
#endif

// async global->LDS, 16B per lane; lds base must be wave-uniform.
static __device__ __forceinline__ void gload16(const void* g, void* l) {
  __builtin_amdgcn_global_load_lds(
      (const __attribute__((address_space(1))) void*)g,
      (__attribute__((address_space(3))) void*)l, 16, 0, 0);
}

// ---------------------------------------------------------------------------
// Prep: z<3: Wq/Wk/Wv [h][d][e] -> Wt3 [which][h][e][d] (bf16);
// z==3: Wo [k][n] -> Wot [n][k] (bf16); z==4: X -> Xb (bf16).
// ---------------------------------------------------------------------------
__global__ __launch_bounds__(256) void prep(
    const float* __restrict__ Wq, const float* __restrict__ Wk,
    const float* __restrict__ Wv, const float* __restrict__ Wo,
    const float* __restrict__ X,
    unsigned short* __restrict__ Wt3, unsigned short* __restrict__ Wot,
    unsigned short* __restrict__ Xb) {
  const int z = blockIdx.z;
  if (z == 4) {
    size_t base = ((size_t)blockIdx.y * 16 + blockIdx.x) * 4096;
#pragma unroll
    for (int it = 0; it < 16; ++it) {
      size_t i = base + it * 256 + threadIdx.x;
      float4 v = ((const float4*)X)[i];
      ushort4 u; u.x = f2bf(v.x); u.y = f2bf(v.y); u.z = f2bf(v.z); u.w = f2bf(v.w);
      ((ushort4*)Xb)[i] = u;
    }
    return;
  }
  __shared__ unsigned short T[64][68];
  const float* src; unsigned short* dst;
  int srcld, dstld, r0, c0;
  if (z < 3) {
    const float* W = (z == 0) ? Wq : (z == 1) ? Wk : Wv;
    unsigned short* Wt = Wt3 + (size_t)z * Dc * Dc;
    int h = blockIdx.y;
    src = W + (size_t)h * Dc * DHc;  srcld = DHc; r0 = blockIdx.x * 64; c0 = 0;
    dst = Wt + (size_t)h * DHc * Dc; dstld = Dc;
  } else {
    src = Wo;  srcld = Dc; r0 = blockIdx.x * 64; c0 = blockIdx.y * 64;
    dst = Wot; dstld = Dc;
  }
#pragma unroll
  for (int it = 0; it < 16; ++it) {
    int idx = it * 256 + threadIdx.x;
    int r = idx >> 6, c = idx & 63;
    T[c][r] = f2bf(src[(size_t)(r0 + r) * srcld + c0 + c]);
  }
  __syncthreads();
#pragma unroll
  for (int it = 0; it < 4; ++it) {
    int idx = it * 256 + threadIdx.x;
    int c = idx >> 4, r4 = (idx & 15) * 4;
    ushort4 u = *(const ushort4*)&T[c][r4];
    *(ushort4*)&dst[(size_t)(c0 + c) * dstld + r0 + r4] = u;
  }
}

// ---------------------------------------------------------------------------
// Unified QKV GEMM: [4096 x 1024] x [1024 x 3072].
// 256x256 tile, BK=64, 8 waves (2M x 4N), 8-phase pipelined K-loop
// (T2 XOR swizzle + T3/T4 counted vmcnt + T5 setprio), 2 K-tiles/iter.
// LDS ring: 4 half-slots [128][64] per operand (128 KiB), unioned with a
// [256][264] epilogue staging buffer (135168 B total -> 1 block/CU).
// Q *(log2e/32) -> Qb[bh][s][e]; K -> Kb; V -> Vtb[bh][e][s] (transposed).
// ---------------------------------------------------------------------------
__global__ __launch_bounds__(512, 2) void qkv_gemm(
    const unsigned short* __restrict__ Xb, const unsigned short* __restrict__ Wt3,
    unsigned short* __restrict__ Qb, unsigned short* __restrict__ Kb,
    unsigned short* __restrict__ Vtb) {
  __shared__ alignas(16) unsigned char smem[135168];
  // Ring view: rows of 64 bf16 (128 B). A slots: rows 0..511 (4 x 128 rows:
  // buf0-A0, buf0-A1, buf1-A0, buf1-A1). B slots: rows 512..1023 likewise.
  unsigned short (*S)[64] = (unsigned short(*)[64])smem;

  const int tid = threadIdx.x;
  const int wv = tid >> 6, lane = tid & 63;
  const int ln = lane & 15, qd = (lane >> 4) & 3;
  const int wm = wv >> 2, wn = wv & 3;   // 2M x 4N wave grid
  const int lr = lane >> 3;
  const int gcol = ((lane & 7) ^ lr) * 8;  // pre-swizzled global k-chunk
  const int paq = ln & 7;

  // XCD-bijective swizzle: 192 blocks, 24 per XCD (192 % 8 == 0).
  const int bid = blockIdx.x;
  const int l = (bid & 7) * 24 + (bid >> 3);
  const int xb = l & 15, y = l >> 4;       // m-tile 0..15, n-tile 0..11
  const int m0 = xb * 256, n0 = y * 256;
  const int which = y >> 2;                // 0=Q 1=K 2=V
  const int b = m0 >> 11, s0 = m0 & 2047;
  const int h0 = (y & 3) * 4;              // 4 heads per 256-col tile

  const unsigned short* Ap = Xb + (size_t)m0 * 1024;
  const unsigned short* Bp = Wt3 + (size_t)n0 * 1024;
  const int grow = wv * 16 + lr;           // global row within a 128-row half

  // Stage one 128x64 half-tile: 2 x gload16 per thread. LDS dest linear
  // (wave-uniform row base); XOR swizzle applied on the GLOBAL source side.
#define STG(gb, srow) do {                                                  \
    gload16((gb) + (size_t)grow * 1024 + gcol,       &S[(srow) + wv * 16][0]); \
    gload16((gb) + (size_t)(grow + 8) * 1024 + gcol, &S[(srow) + wv * 16 + 8][0]); \
  } while (0)

#define RD_A(mh, rowbase) do {                                              \
    _Pragma("unroll") for (int mt = 0; mt < 4; ++mt)                        \
      _Pragma("unroll") for (int ks = 0; ks < 2; ++ks)                      \
        af[mt][ks] = *(const bf16x8*)&S[(rowbase) + (mh) * 64 + mt * 16 + ln] \
                                       [((ks * 4 + qd) ^ paq) * 8];         \
  } while (0)

#define RD_B(nh, rowbase) do {                                              \
    _Pragma("unroll") for (int nt = 0; nt < 2; ++nt)                        \
      _Pragma("unroll") for (int ks = 0; ks < 2; ++ks)                      \
        bf[(nh) * 2 + nt][ks] = *(const bf16x8*)&S[(rowbase) + (nh) * 32 + nt * 16 + ln] \
                                                  [((ks * 4 + qd) ^ paq) * 8]; \
  } while (0)

#define MM(mh, nh) do {                                                     \
    _Pragma("unroll") for (int ks = 0; ks < 2; ++ks)                        \
      _Pragma("unroll") for (int mt = 0; mt < 4; ++mt)                      \
        _Pragma("unroll") for (int nt = 0; nt < 2; ++nt)                    \
          acc[(mh) * 4 + mt][(nh) * 2 + nt] =                               \
              __builtin_amdgcn_mfma_f32_16x16x32_bf16(                      \
                  af[mt][ks], bf[(nh) * 2 + nt][ks],                        \
                  acc[(mh) * 4 + mt][(nh) * 2 + nt], 0, 0, 0);              \
  } while (0)

#define BAR __builtin_amdgcn_s_barrier()
#define WAITL asm volatile("s_waitcnt lgkmcnt(0)" ::: "memory")
#define WAITV(n) asm volatile("s_waitcnt vmcnt(" #n ")" ::: "memory")
#define PRIO1 __builtin_amdgcn_s_setprio(1)
#define PRIO0 __builtin_amdgcn_s_setprio(0)

  f32x4 acc[8][4];
#pragma unroll
  for (int mt = 0; mt < 8; ++mt)
#pragma unroll
    for (int nt = 0; nt < 4; ++nt) acc[mt][nt] = (f32x4){0.f, 0.f, 0.f, 0.f};

  // Prologue: tile0 fully + tile1's B0,A0. (A row offset +128*1024 = half 1;
  // k offset kt*64 elements.)
  STG(Bp, 512);                 // B0(t0)
  STG(Ap, 0);                   // A0(t0)
  STG(Ap + 128 * 1024, 128);    // A1(t0)
  STG(Bp + 128 * 1024, 640);    // B1(t0)
  STG(Bp + 64, 768);            // B0(t1)
  STG(Ap + 64, 256);            // A0(t1)
  WAITV(4);                     // tile0 landed; B0/A0(t1) may fly
  BAR;

  bf16x8 af[4][2], bf[4][2];

  for (int j = 0; j < 8; ++j) {
    const int last = (j == 7);
    const unsigned short* Ak = Ap + j * 128;  // k elem offset of tile 2j
    const unsigned short* Bk = Bp + j * 128;

    // ---- tile 2j (buf0) ----
    // P0: stage A1(2j+1); compute quadrant (mh0, nh0)
    STG(Ak + 128 * 1024 + 64, 384);
    RD_A(0, wm * 128);
    RD_B(0, 512 + (wn >> 1) * 128 + (wn & 1) * 64);
    BAR; WAITL;
    PRIO1; MM(0, 0); PRIO0; BAR;
    // P1: stage B1(2j+1); quadrant (mh0, nh1)
    STG(Bk + 128 * 1024 + 64, 896);
    RD_B(1, 512 + (wn >> 1) * 128 + (wn & 1) * 64);
    BAR; WAITL;
    PRIO1; MM(0, 1); PRIO0; BAR;
    // P2: stage B0(2j+2); quadrant (mh1, nh0)
    if (!last) STG(Bk + 128, 512);
    RD_A(1, wm * 128);
    BAR; WAITL;
    PRIO1; MM(1, 0); PRIO0; BAR;
    // P3: stage A0(2j+2); quadrant (mh1, nh1); tile-boundary wait
    if (!last) STG(Ak + 128, 0);
    BAR;
    PRIO1; MM(1, 1); PRIO0;
    if (last) { WAITV(0); } else { WAITV(4); }  // tile 2j+1 fully landed
    BAR;

    // ---- tile 2j+1 (buf1) ----
    // P4: stage A1(2j+2); quadrant (mh0, nh0)
    if (!last) STG(Ak + 128 * 1024 + 128, 128);
    RD_A(0, 256 + wm * 128);
    RD_B(0, 768 + (wn >> 1) * 128 + (wn & 1) * 64);
    BAR; WAITL;
    PRIO1; MM(0, 0); PRIO0; BAR;
    // P5: stage B1(2j+2); quadrant (mh0, nh1)
    if (!last) STG(Bk + 128 * 1024 + 128, 640);
    RD_B(1, 768 + (wn >> 1) * 128 + (wn & 1) * 64);
    BAR; WAITL;
    PRIO1; MM(0, 1); PRIO0; BAR;
    // P6: stage B0(2j+3); quadrant (mh1, nh0)
    if (!last) STG(Bk + 192, 768);
    RD_A(1, 256 + wm * 128);
    BAR; WAITL;
    PRIO1; MM(1, 0); PRIO0; BAR;
    // P7: stage A0(2j+3); quadrant (mh1, nh1); tile-boundary wait
    if (!last) STG(Ak + 192, 256);
    BAR;
    PRIO1; MM(1, 1); PRIO0;
    if (!last) WAITV(4);                       // tile 2j+2 fully landed
    BAR;
  }

  // Epilogue: restage C through LDS (pitch 264 -> 16B-aligned rows).
  unsigned short* Ts = (unsigned short*)smem;
  if (which < 2) {
    unsigned short* Out = (which == 0) ? Qb : Kb;
    const float scale = (which == 0) ? (LOG2E / 32.0f) : 1.0f;
#pragma unroll
    for (int mt = 0; mt < 8; ++mt)
#pragma unroll
      for (int nt = 0; nt < 4; ++nt)
#pragma unroll
        for (int r = 0; r < 4; ++r)
          Ts[(wm * 128 + mt * 16 + qd * 4 + r) * 264 + wn * 64 + nt * 16 + ln] =
              f2bf(acc[mt][nt][r] * scale);
    __syncthreads();
    const int row = tid >> 1;
#pragma unroll
    for (int it = 0; it < 16; ++it) {
      int c16 = (tid & 1) * 16 + it;        // 16B chunk 0..31
      int head = c16 >> 3, e8 = c16 & 7;
      *(ulonglong2*)&Out[(((size_t)b * Hc + h0 + head) * Sc + s0 + row) * DHc + e8 * 8] =
          *(const ulonglong2*)&Ts[row * 264 + c16 * 8];
    }
  } else {
    // V: stage transposed [n][s] so stores to Vtb[bh][e][s] are 16B row-linear.
#pragma unroll
    for (int mt = 0; mt < 8; ++mt)
#pragma unroll
      for (int nt = 0; nt < 4; ++nt)
#pragma unroll
        for (int r = 0; r < 4; ++r)
          Ts[(wn * 64 + nt * 16 + ln) * 264 + wm * 128 + mt * 16 + qd * 4 + r] =
              f2bf(acc[mt][nt][r]);
    __syncthreads();
    const int n = tid >> 1;
    const int head = n >> 6, e = n & 63;
    unsigned short* dst = Vtb + (((size_t)b * Hc + h0 + head) * DHc + e) * Sc + s0;
#pragma unroll
    for (int it = 0; it < 16; ++it) {
      int s16 = (tid & 1) * 16 + it;
      *(ulonglong2*)&dst[s16 * 8] = *(const ulonglong2*)&Ts[n * 264 + s16 * 8];
    }
  }
#undef STG
#undef RD_A
#undef RD_B
#undef MM
#undef BAR
#undef WAITL
#undef WAITV
#undef PRIO1
#undef PRIO0
}

// ---------------------------------------------------------------------------
// Flash attention partial, bf16 MFMA, no-max softmax in exp2 domain.
// grid (8 sT, 32 bh, 2 sp); block 256 = 4 waves; Q-block 256 rows,
// wave owns 64 rows (4 m-tiles) -> MFMA:LDS ratio ~1.8 per iter.
// S^T = K*Q^T; P packed via v_perm trunc; l via MFMA ones-column.
// ---------------------------------------------------------------------------
__global__ __launch_bounds__(256, 2) void attn_partial(
    const unsigned short* __restrict__ Qb, const unsigned short* __restrict__ Kb,
    const unsigned short* __restrict__ Vtb,
    unsigned short* __restrict__ Opart, float* __restrict__ lpart) {
  __shared__ alignas(16) unsigned short Ks[64][64];   // K tile  [n][e] swizzled
  __shared__ alignas(16) unsigned short Vts[64][64];  // Vt tile [e][n] swizzled
  __shared__ alignas(16) unsigned short Ps[256][64];  // P tile  [m][n] swizzled

  const int tid = threadIdx.x;
  const int wv = tid >> 6, lane = tid & 63;
  const int ln = tid & 15, qd = (tid >> 4) & 3;
  const int sT = blockIdx.x, bh = blockIdx.y, sp = blockIdx.z;
  const int lr = lane >> 3;
  const int lcs = ((lane & 7) ^ lr) * 8;

  // Q fragments (64 rows/wave) in registers for all 16 key tiles.
  bf16x8 qf[4][2];
  const size_t qrow0 = (size_t)bh * Sc + sT * 256 + wv * 64;
#pragma unroll
  for (int mt = 0; mt < 4; ++mt)
#pragma unroll
    for (int ks = 0; ks < 2; ++ks)
      qf[mt][ks] = *(const bf16x8*)&Qb[(qrow0 + mt * 16 + ln) * DHc + ks * 32 + qd * 8];

  bf16x8 vones;
#pragma unroll
  for (int j = 0; j < 8; ++j) vones[j] = (short)0x3F80;  // 1.0 bf16

  f32x4 o[4][4], lacc[4];
#pragma unroll
  for (int mt = 0; mt < 4; ++mt) {
    lacc[mt] = (f32x4){0.f, 0.f, 0.f, 0.f};
#pragma unroll
    for (int et = 0; et < 4; ++et) o[mt][et] = (f32x4){0.f, 0.f, 0.f, 0.f};
  }

  for (int kb = sp * 16; kb < sp * 16 + 16; ++kb) {
    __syncthreads();
#pragma unroll
    for (int t = 0; t < 2; ++t) {
      gload16(Kb  + ((size_t)bh * Sc + kb * 64 + wv * 16 + t * 8 + lr) * DHc + lcs,
              &Ks[wv * 16 + t * 8][0]);
      gload16(Vtb + ((size_t)bh * DHc + wv * 16 + t * 8 + lr) * Sc + kb * 64 + lcs,
              &Vts[wv * 16 + t * 8][0]);
    }
    __syncthreads();

    // S^T = K Q^T : lane holds S[m=mt*16+ln][n=nt*16+qd*4+r].
    f32x4 st[4][4];
#pragma unroll
    for (int mt = 0; mt < 4; ++mt)
#pragma unroll
      for (int nt = 0; nt < 4; ++nt) st[mt][nt] = (f32x4){0.f, 0.f, 0.f, 0.f};
#pragma unroll
    for (int ks = 0; ks < 2; ++ks) {
      const int pa = ((ks * 4 + qd) ^ (ln & 7)) * 8;
#pragma unroll
      for (int nt = 0; nt < 4; ++nt) {
        bf16x8 kf = *(const bf16x8*)&Ks[nt * 16 + ln][pa];
#pragma unroll
        for (int mt = 0; mt < 4; ++mt)
          st[mt][nt] = __builtin_amdgcn_mfma_f32_16x16x32_bf16(kf, qf[mt][ks], st[mt][nt], 0, 0, 0);
      }
    }

    // p = 2^s (scores tiny; no max). Pack trunc-bf16 pairs with v_perm.
#pragma unroll
    for (int mt = 0; mt < 4; ++mt) {
      const int prow = wv * 64 + mt * 16 + ln;
#pragma unroll
      for (int nt = 0; nt < 4; ++nt) {
        float p0 = EXP2F(st[mt][nt][0]);
        float p1 = EXP2F(st[mt][nt][1]);
        float p2 = EXP2F(st[mt][nt][2]);
        float p3 = EXP2F(st[mt][nt][3]);
        uint2 w;
        w.x = pk2bf_trunc(p0, p1);
        w.y = pk2bf_trunc(p2, p3);
        int ppos = ((2 * nt + (qd >> 1)) ^ (ln & 7)) * 8 + (qd & 1) * 4;
        *(uint2*)&Ps[prow][ppos] = w;
      }
    }
    __syncthreads();

    // O += P V ; l += P 1.
#pragma unroll
    for (int ks = 0; ks < 2; ++ks) {
      const int pa = ((ks * 4 + qd) ^ (ln & 7)) * 8;
      bf16x8 pf[4];
#pragma unroll
      for (int mt = 0; mt < 4; ++mt) {
        pf[mt] = *(const bf16x8*)&Ps[wv * 64 + mt * 16 + ln][pa];
        lacc[mt] = __builtin_amdgcn_mfma_f32_16x16x32_bf16(pf[mt], vones, lacc[mt], 0, 0, 0);
      }
#pragma unroll
      for (int et = 0; et < 4; ++et) {
        bf16x8 vf = *(const bf16x8*)&Vts[et * 16 + ln][pa];
#pragma unroll
        for (int mt = 0; mt < 4; ++mt)
          o[mt][et] = __builtin_amdgcn_mfma_f32_16x16x32_bf16(pf[mt], vf, o[mt][et], 0, 0, 0);
      }
    }
  }

  // Partials: rows indexed (sp, bh, sT, 256 rows).
  const size_t pbase = (size_t)sp * 65536 + ((size_t)bh * 8 + sT) * 256;
  if (ln == 0) {
#pragma unroll
    for (int mt = 0; mt < 4; ++mt)
#pragma unroll
      for (int r = 0; r < 4; ++r)
        lpart[pbase + wv * 64 + mt * 16 + qd * 4 + r] = lacc[mt][r];
  }
#pragma unroll
  for (int mt = 0; mt < 4; ++mt)
#pragma unroll
    for (int r = 0; r < 4; ++r) {
      int row = wv * 64 + mt * 16 + qd * 4 + r;
#pragma unroll
      for (int et = 0; et < 4; ++et)
        Opart[(pbase + row) * DHc + et * 16 + ln] = f2bf(o[mt][et][r]);
    }
}

// ---------------------------------------------------------------------------
// Combine: Ocat[b][s][h*64+e] = (O0+O1)/(l0+l1), bf16 out. grid (8,32).
// ---------------------------------------------------------------------------
__global__ __launch_bounds__(256) void combine(
    const unsigned short* __restrict__ Opart, const float* __restrict__ lpart,
    unsigned short* __restrict__ Ocat) {
  const int sT = blockIdx.x, bh = blockIdx.y, tid = threadIdx.x;
  const int b = bh >> 4, h = bh & 15;
  const size_t p0 = ((size_t)bh * 8 + sT) * 256;
  const size_t p1 = p0 + 65536;
#pragma unroll
  for (int it = 0; it < 16; ++it) {
    int idx = it * 256 + tid;
    int row = idx >> 4, c4 = (idx & 15) * 4;
    ushort4 u0 = *(const ushort4*)&Opart[(p0 + row) * DHc + c4];
    ushort4 u1 = *(const ushort4*)&Opart[(p1 + row) * DHc + c4];
    float inv = 1.0f / (lpart[p0 + row] + lpart[p1 + row]);
    ushort4 w;
    w.x = f2bf((bf2f(u0.x) + bf2f(u1.x)) * inv);
    w.y = f2bf((bf2f(u0.y) + bf2f(u1.y)) * inv);
    w.z = f2bf((bf2f(u0.z) + bf2f(u1.z)) * inv);
    w.w = f2bf((bf2f(u0.w) + bf2f(u1.w)) * inv);
    *(ushort4*)&Ocat[((size_t)b * Sc + sT * 256 + row) * Dc + h * DHc + c4] = w;
  }
}

// ---------------------------------------------------------------------------
// Output projection, bf16 MFMA. Tile 64x128, grid (64,8). XOR-swizzled.
// ---------------------------------------------------------------------------
__global__ __launch_bounds__(256) void out_gemm(
    const unsigned short* __restrict__ Ab, const unsigned short* __restrict__ Wot,
    const float* __restrict__ bo, float* __restrict__ Out) {
  __shared__ alignas(16) unsigned short As[64][64];
  __shared__ alignas(16) unsigned short Bs[128][64];  // [n][k]

  const int tid = threadIdx.x;
  const int wv = tid >> 6, lane = tid & 63;
  const int ln = tid & 15, qd = (tid >> 4) & 3;
  const int wm = wv >> 1, wn = wv & 1;
  const int m0 = blockIdx.x * 64, n0 = blockIdx.y * 128;
  const int lr = lane >> 3;
  const int lcs = ((lane & 7) ^ lr) * 8;

  f32x4 acc[2][4];
#pragma unroll
  for (int mt = 0; mt < 2; ++mt)
#pragma unroll
    for (int nt = 0; nt < 4; ++nt) acc[mt][nt] = (f32x4){0.f, 0.f, 0.f, 0.f};

  for (int k0 = 0; k0 < Dc; k0 += 64) {
    __syncthreads();
#pragma unroll
    for (int t = 0; t < 2; ++t)
      gload16(Ab + (size_t)(m0 + wv * 16 + t * 8 + lr) * Dc + k0 + lcs, &As[wv * 16 + t * 8][0]);
#pragma unroll
    for (int t = 0; t < 4; ++t)
      gload16(Wot + (size_t)(n0 + wv * 32 + t * 8 + lr) * Dc + k0 + lcs, &Bs[wv * 32 + t * 8][0]);
    __syncthreads();
#pragma unroll
    for (int ks = 0; ks < 2; ++ks) {
      const int pa = ((ks * 4 + qd) ^ (ln & 7)) * 8;
      bf16x8 af[2], bf[4];
#pragma unroll
      for (int mt = 0; mt < 2; ++mt)
        af[mt] = *(const bf16x8*)&As[wm * 32 + mt * 16 + ln][pa];
#pragma unroll
      for (int nt = 0; nt < 4; ++nt)
        bf[nt] = *(const bf16x8*)&Bs[wn * 64 + nt * 16 + ln][pa];
#pragma unroll
      for (int mt = 0; mt < 2; ++mt)
#pragma unroll
        for (int nt = 0; nt < 4; ++nt)
          acc[mt][nt] = __builtin_amdgcn_mfma_f32_16x16x32_bf16(af[mt], bf[nt], acc[mt][nt], 0, 0, 0);
    }
  }

  float bias[4];
#pragma unroll
  for (int nt = 0; nt < 4; ++nt) bias[nt] = bo[n0 + wn * 64 + nt * 16 + ln];

#pragma unroll
  for (int mt = 0; mt < 2; ++mt)
#pragma unroll
    for (int r = 0; r < 4; ++r) {
      int m = m0 + wm * 32 + mt * 16 + qd * 4 + r;
#pragma unroll
      for (int nt = 0; nt < 4; ++nt)
        Out[(size_t)m * Dc + n0 + wn * 64 + nt * 16 + ln] = acc[mt][nt][r] + bias[nt];
    }
}

// ---------------------------------------------------------------------------
extern "C" void kernel_launch(void* const* d_in, const int* in_sizes, int n_in,
                              void* d_out, int out_size, void* d_ws, size_t ws_size,
                              hipStream_t stream) {
  (void)in_sizes; (void)n_in; (void)out_size; (void)ws_size;
  const float* X  = (const float*)d_in[0];
  const float* Wq = (const float*)d_in[1];
  const float* Wk = (const float*)d_in[2];
  const float* Wv = (const float*)d_in[3];
  const float* Wo = (const float*)d_in[4];
  const float* bo = (const float*)d_in[5];
  float* out = (float*)d_out;

  const size_t nX = (size_t)Bc * Sc * Dc;  // 4 Mi
  unsigned short* Xb    = (unsigned short*)d_ws;
  unsigned short* Wt3   = Xb + nX;
  unsigned short* Wot   = Wt3 + (size_t)3 * Dc * Dc;
  unsigned short* Qb    = Wot + (size_t)Dc * Dc;
  unsigned short* Kb    = Qb + nX;
  unsigned short* Vtb   = Kb + nX;
  unsigned short* Opart = Vtb + nX;
  float* lpart = (float*)(Opart + 2 * nX);
  unsigned short* Ocat = Xb;  // alias: Xb dead after qkv_gemm

  prep<<<dim3(16, 16, 5), 256, 0, stream>>>(Wq, Wk, Wv, Wo, X, Wt3, Wot, Xb);
  qkv_gemm<<<dim3(192), 512, 0, stream>>>(Xb, Wt3, Qb, Kb, Vtb);
  attn_partial<<<dim3(8, 32, 2), 256, 0, stream>>>(Qb, Kb, Vtb, Opart, lpart);
  combine<<<dim3(8, 32), 256, 0, stream>>>(Opart, lpart, Ocat);
  out_gemm<<<dim3(64, 8), 256, 0, stream>>>(Ocat, Wot, bo, out);
}